// Round 14
// baseline (256.067 us; speedup 1.0000x reference)
//
#include <hip/hip_runtime.h>
#include <hip/hip_bf16.h>

typedef unsigned short u16;
typedef unsigned int u32;
typedef unsigned long long u64;
typedef short s8v __attribute__((ext_vector_type(8)));
typedef short s4v __attribute__((ext_vector_type(4)));
typedef __bf16 bfv8 __attribute__((ext_vector_type(8)));
typedef float f4 __attribute__((ext_vector_type(4)));

static constexpr int B = 2, D = 1024, L = 2048, H = 16, DK = 64, E = 1024;
// fold 1/sqrt(DK) and log2(e) into Q so softmax runs natively in exp2 domain
static constexpr float QSCALE = 0.125f * 1.44269504088896340736f;
static constexpr float SMB = -16.0f;       // fixed softmax bias (|s|<~10)
static constexpr float MASKB = -12000.0f;  // exp2(MASKB+s) == 0.0f exactly

#define DEV __device__ __forceinline__

DEV u16 f2bf(float f) {  // fp32 -> bf16 round-to-nearest-even
  unsigned int u = __float_as_uint(f);
  u += 0x7FFFu + ((u >> 16) & 1u);
  return (u16)(u >> 16);
}
DEV float fexp2(float x) { return __builtin_amdgcn_exp2f(x); }
DEV u32 pkbf(float a, float b) {  // packed fp32x2 -> bf16x2 (v_cvt_pk)
  __hip_bfloat162 h = __float22bfloat162_rn(float2{a, b});
  u32 r;
  __builtin_memcpy(&r, &h, 4);
  return r;
}

// K=16 bf16 MFMA (v_mfma_f32_16x16x16_bf16, 2 A / 2 B / 4 C regs).
DEV f4 mfma16(s4v a, s4v b, f4 c) {
  return __builtin_amdgcn_mfma_f32_16x16x16bf16_1k(a, b, c, 0, 0, 0);
}

#define GLD_LDS16(gp, lp)                                                     \
  __builtin_amdgcn_global_load_lds(                                           \
      (const __attribute__((address_space(1))) void*)(gp),                    \
      (__attribute__((address_space(3))) void*)(lp), 16, 0, 0)

// ---------- Kernel 0: fused fp32->bf16 64x64 tile transposes ----------
__global__ __launch_bounds__(256) void k_prep(
    const float* __restrict__ x, const float* __restrict__ Wq,
    const float* __restrict__ Wk, const float* __restrict__ Wv,
    const float* __restrict__ Wo, u16* __restrict__ xt, u16* __restrict__ Wt,
    u16* __restrict__ WoT) {
  __shared__ u16 t[64][67];
  const int tid = threadIdx.x;
  const int g = blockIdx.x;
  const float* src;
  u16* dst;
  int sld, dld;
  if (g < 1024) {
    const int b = g >> 9, dt = (g >> 5) & 15, lt = g & 31;
    src = x + ((size_t)b * D + dt * 64) * L + lt * 64;
    sld = L;
    dst = xt + ((size_t)b * L + lt * 64) * D + dt * 64;
    dld = D;
  } else if (g < 1792) {
    const int u = g - 1024;
    const int w = u >> 8, h = (u >> 4) & 15, dt = u & 15;
    const float* Ws = (w == 0) ? Wq : ((w == 1) ? Wk : Wv);
    src = Ws + ((size_t)h * D + dt * 64) * DK;
    sld = DK;
    dst = Wt + ((size_t)(w * H + h) * DK) * D + dt * 64;
    dld = D;
  } else {
    const int v = g - 1792;
    const int et = v >> 4, dt = v & 15;
    src = Wo + ((size_t)et * 64) * D + dt * 64;
    sld = D;
    dst = WoT + ((size_t)dt * 64) * E + et * 64;
    dld = E;
  }
  const int r = tid >> 2, c16 = (tid & 3) * 16;
#pragma unroll
  for (int j = 0; j < 16; j += 4) {
    const f4 v4 = *(const f4*)(src + (size_t)r * sld + c16 + j);
    t[r][c16 + j]     = f2bf(v4[0]);
    t[r][c16 + j + 1] = f2bf(v4[1]);
    t[r][c16 + j + 2] = f2bf(v4[2]);
    t[r][c16 + j + 3] = f2bf(v4[3]);
  }
  __syncthreads();
  s8v o0, o1;
#pragma unroll
  for (int i = 0; i < 8; ++i) {
    o0[i] = (short)t[c16 + i][r];
    o1[i] = (short)t[c16 + 8 + i][r];
  }
  *(s8v*)(dst + (size_t)r * dld + c16)     = o0;
  *(s8v*)(dst + (size_t)r * dld + c16 + 8) = o1;
}

// ---------- shared GEMM tile core: BK=64, single-buffer, 1 barrier-pair ----
// LDS tiles [rows][64] u16 (128B rows), swizzle phys_chunk = logical^(row&7).
template <int AR>
DEV void gemm_tile(const u16* __restrict__ A, const u16* __restrict__ Bt,
                   int arow0, int brow0, u16* As, u16* Bs,
                   f4 (&acc)[AR / 32][4]) {
  const int tid = threadIdx.x;
  const int wid = tid >> 6, lane = tid & 63;
  const int q = lane >> 4, ln = lane & 15;
  const int wr = wid >> 1, wc = wid & 1;
  const int lrow = lane >> 3;        // 0..7 (dest row & 7)
  const int lc = (lane & 7) ^ lrow;  // logical chunk for swizzled dest
  const int f0 = (q ^ (ln & 7)) * 8;        // frag phys chunk, k-step 0
  const int f1 = ((q + 4) ^ (ln & 7)) * 8;  // k-step 1
  constexpr int MT = AR / 32;

  for (int k0 = 0; k0 < 1024; k0 += 64) {
    __syncthreads();
#pragma unroll
    for (int j = 0; j < AR / 32; ++j) {  // A: 8 rows per instr
      const int rb = wid * (AR / 4) + j * 8;
      GLD_LDS16(A + (size_t)(arow0 + rb + lrow) * 1024 + k0 + lc * 8,
                As + rb * 64);
    }
#pragma unroll
    for (int j = 0; j < 4; ++j) {  // B: 128 rows
      const int rb = wid * 32 + j * 8;
      GLD_LDS16(Bt + (size_t)(brow0 + rb + lrow) * 1024 + k0 + lc * 8,
                Bs + rb * 64);
    }
    __syncthreads();
#pragma unroll
    for (int ks = 0; ks < 2; ++ks) {
      const int fc = ks ? f1 : f0;
      bfv8 af[MT], bf[4];
#pragma unroll
      for (int mt = 0; mt < MT; ++mt)
        af[mt] = *(const bfv8*)(As + (wr * (AR / 2) + mt * 16 + ln) * 64 + fc);
#pragma unroll
      for (int nt = 0; nt < 4; ++nt)
        bf[nt] = *(const bfv8*)(Bs + (wc * 64 + nt * 16 + ln) * 64 + fc);
#pragma unroll
      for (int mt = 0; mt < MT; ++mt)
#pragma unroll
        for (int nt = 0; nt < 4; ++nt)
          acc[mt][nt] = __builtin_amdgcn_mfma_f32_16x16x32_bf16(
              af[mt], bf[nt], acc[mt][nt], 0, 0, 0);
    }
  }
}

// ---------- Kernel 1: QKV projection as one GEMM ----------
__global__ __launch_bounds__(256, 3) void k_qkvg(
    const u16* __restrict__ xt, const u16* __restrict__ Wt,
    u16* __restrict__ Q, u16* __restrict__ K, u16* __restrict__ Vt) {
  __shared__ u16 As[128 * 64];  // 16 KB
  __shared__ u16 Bs[128 * 64];  // 16 KB  (32 KB total: 3 blocks/CU ok)
  const int bm = blockIdx.x, bn = blockIdx.y;
  f4 acc[4][4];
#pragma unroll
  for (int mt = 0; mt < 4; ++mt)
#pragma unroll
    for (int nt = 0; nt < 4; ++nt) acc[mt][nt] = (f4){0.f, 0.f, 0.f, 0.f};
  gemm_tile<128>(xt, Wt, bm * 128, bn * 128, As, Bs, acc);

  const int tid = threadIdx.x, wid = tid >> 6, lane = tid & 63;
  const int q = lane >> 4, ln = lane & 15;
  const int wr = wid >> 1, wc = wid & 1;
  const int h2 = bn * 2 + wc;  // 0..47
  const int wsel = h2 >> 4, h = h2 & 15;
  const int b = bm >> 4;
  const int lbase = (bm & 15) * 128 + wr * 64;
  if (wsel == 0) {
    u16* dst = Q + (size_t)(b * H + h) * L * DK;
#pragma unroll
    for (int mt = 0; mt < 4; ++mt)
#pragma unroll
      for (int nt = 0; nt < 4; ++nt)
#pragma unroll
        for (int r = 0; r < 4; ++r)
          dst[(size_t)(lbase + mt * 16 + q * 4 + r) * DK + nt * 16 + ln] =
              f2bf(acc[mt][nt][r] * QSCALE);
  } else if (wsel == 1) {
    u16* dst = K + (size_t)(b * H + h) * L * DK;
#pragma unroll
    for (int mt = 0; mt < 4; ++mt)
#pragma unroll
      for (int nt = 0; nt < 4; ++nt)
#pragma unroll
        for (int r = 0; r < 4; ++r)
          dst[(size_t)(lbase + mt * 16 + q * 4 + r) * DK + nt * 16 + ln] =
              f2bf(acc[mt][nt][r]);
  } else {
    // V: plain transpose Vt[dk][l], 4 consecutive l per lane -> 8B stores
    u16* dst = Vt + (size_t)(b * H + h) * DK * L;
#pragma unroll
    for (int mt = 0; mt < 4; ++mt)
#pragma unroll
      for (int nt = 0; nt < 4; ++nt) {
        const u64 pk = (u64)pkbf(acc[mt][nt][0], acc[mt][nt][1]) |
                       ((u64)pkbf(acc[mt][nt][2], acc[mt][nt][3]) << 32);
        *(u64*)(dst + (size_t)(nt * 16 + ln) * L + lbase + mt * 16 + q * 4) =
            pk;
      }
  }
}

// ---------- Kernel 2: flash attention, K dbuf-LDS, V direct-from-global ----
// kt dbuf 32 KB + mb 8 KB = 40 KB -> 4 blocks/CU (4 waves/SIMD). V fragments
// are barrier-free 8B global loads (L2-hot: h-major grid pins the (b,h) Vt
// slice to one XCD). Single-barrier prefetch loop = R11-proven structure.
__global__ __launch_bounds__(256, 4) void k_attn(
    const u16* __restrict__ Q, const u16* __restrict__ K,
    const u16* __restrict__ Vt, const float* __restrict__ mask,
    u16* __restrict__ Hd) {
  __shared__ u16 kt[2][128 * 64];  // [key][dk], chunk-swizzled c^=(row&7)
  __shared__ __align__(16) float mb[L];  // per-key bias: SMB or MASKB
  const int h = blockIdx.x, lt = blockIdx.y, b = blockIdx.z;
  const int tid = threadIdx.x;
  const int w = tid >> 6, lane = tid & 63, q = lane >> 4, ln = lane & 15;
  for (int i = tid; i < L; i += 256)
    mb[i] = (mask[(size_t)b * L + i] != 0.0f) ? SMB : MASKB;

  const int bh = b * H + h;
  const u16* Qp = Q + (size_t)bh * L * DK;
  const u16* Kp = K + (size_t)bh * L * DK;
  const u16* Vp = Vt + (size_t)bh * DK * L;
  const int lq = lt * 128 + w * 32;  // wave covers 32 q-rows

  bfv8 qf[2][2];
#pragma unroll
  for (int mt = 0; mt < 2; ++mt) {
    qf[mt][0] = *(const bfv8*)(Qp + (size_t)(lq + mt * 16 + ln) * DK + q * 8);
    qf[mt][1] =
        *(const bfv8*)(Qp + (size_t)(lq + mt * 16 + ln) * DK + 32 + q * 8);
  }

  const int lrow = lane >> 3;        // 0..7 (== dest row & 7)
  const int lc = (lane & 7) ^ lrow;  // logical chunk for swizzled dest
  const int c0 = (q ^ (ln & 7)) * 8;        // K-frag phys chunk, low dk half
  const int c1 = ((q + 4) ^ (ln & 7)) * 8;  // high dk half

  auto stageK = [&](int m0, int bufi) {  // key-rows [w*32, w*32+32)
#pragma unroll
    for (int j = 0; j < 4; ++j) {
      const int rb = w * 32 + j * 8;
      GLD_LDS16(Kp + (size_t)(m0 + rb + lrow) * DK + lc * 8,
                &kt[bufi][rb * 64]);
    }
  };

  f4 ot[2][4];  // O^T[dk=dt*16+q*4+r][qrow=mt*16+ln]
#pragma unroll
  for (int mt = 0; mt < 2; ++mt)
#pragma unroll
    for (int i = 0; i < 4; ++i) ot[mt][i] = (f4){0.f, 0.f, 0.f, 0.f};
  float lp[2] = {0.f, 0.f};  // partial row-sums (this quad's keys)

  stageK(0, 0);
  for (int it = 0; it < L / 128; ++it) {
    const int m0 = it * 128;
    __syncthreads();  // kt[it&1] landed; mb ready; kt[(it+1)&1] reads done
    if (it + 1 < L / 128) stageK(m0 + 128, (it + 1) & 1);
    const u16* ktc = &kt[it & 1][0];

    // QK^T swapped (D[m=key][n=qrow]) fused with exp2+pack per 16-key strip
    s4v pb[2][8];
#pragma unroll
    for (int nt = 0; nt < 8; ++nt) {
      const int krow = nt * 16 + ln;  // krow&7 == ln&7: c0/c1 valid
      const bfv8 kf0 = *(const bfv8*)(ktc + krow * 64 + c0);
      const bfv8 kf1 = *(const bfv8*)(ktc + krow * 64 + c1);
      const f4 mbv = *(const f4*)(mb + m0 + nt * 16 + q * 4);
#pragma unroll
      for (int mt = 0; mt < 2; ++mt) {
        f4 a = mbv;  // mask bias in accumulator init
        a = __builtin_amdgcn_mfma_f32_16x16x32_bf16(kf0, qf[mt][0], a, 0, 0,
                                                    0);
        a = __builtin_amdgcn_mfma_f32_16x16x32_bf16(kf1, qf[mt][1], a, 0, 0,
                                                    0);
        const float p0 = fexp2(a[0]);  // masked keys: exact 0
        const float p1 = fexp2(a[1]);
        const float p2 = fexp2(a[2]);
        const float p3 = fexp2(a[3]);
        lp[mt] += (p0 + p1) + (p2 + p3);
        const u64 pk = (u64)pkbf(p0, p1) | ((u64)pkbf(p2, p3) << 32);
        pb[mt][nt] = __builtin_bit_cast(s4v, pk);
      }
    }
    // O^T += V^T . P^T  — V A-frags DIRECT from global (no barrier, no LDS):
    // av[kc] = Vt[dk=dt*16+ln][m0 + kh*64 + kc*16 + q*4 .. +4]  (8B loads)
#pragma unroll
    for (int kh = 0; kh < 2; ++kh) {
#pragma unroll
      for (int dt = 0; dt < 4; ++dt) {
        const u16* vg =
            Vp + (size_t)(dt * 16 + ln) * L + m0 + kh * 64 + q * 4;
        s4v av[4];
#pragma unroll
        for (int kc = 0; kc < 4; ++kc) av[kc] = *(const s4v*)(vg + kc * 16);
#pragma unroll
        for (int kc = 0; kc < 4; ++kc)
#pragma unroll
          for (int mt = 0; mt < 2; ++mt)
            ot[mt][dt] = mfma16(av[kc], pb[mt][kh * 4 + kc], ot[mt][dt]);
      }
    }
  }
  // row-sum: reduce across the 4 quads (same qrow), normalize, store
#pragma unroll
  for (int mt = 0; mt < 2; ++mt) {
    lp[mt] += __shfl_xor(lp[mt], 16);
    lp[mt] += __shfl_xor(lp[mt], 32);
    const float linv =
        (mb[lq + mt * 16 + ln] > -100.0f) ? (1.0f / lp[mt]) : 0.0f;
#pragma unroll
    for (int dt = 0; dt < 4; ++dt) {
      const u64 pk =
          (u64)pkbf(ot[mt][dt][0] * linv, ot[mt][dt][1] * linv) |
          ((u64)pkbf(ot[mt][dt][2] * linv, ot[mt][dt][3] * linv) << 32);
      *(u64*)(Hd + (size_t)(b * L + lq + mt * 16 + ln) * E + h * DK + dt * 16 +
              q * 4) = pk;
    }
  }
}

// ---------- Kernel 3: output projection as GEMM ----------
__global__ __launch_bounds__(256, 2) void k_projg(const u16* __restrict__ WoT,
                                                  const u16* __restrict__ Hd,
                                                  float* __restrict__ out) {
  __shared__ u16 As[64 * 64];   // 8 KB
  __shared__ u16 Bs[128 * 64];  // 16 KB
  const int bm = blockIdx.x, bn = blockIdx.y;
  f4 acc[2][4];
#pragma unroll
  for (int mt = 0; mt < 2; ++mt)
#pragma unroll
    for (int nt = 0; nt < 4; ++nt) acc[mt][nt] = (f4){0.f, 0.f, 0.f, 0.f};
  gemm_tile<64>(WoT, Hd, bm * 64, bn * 128, As, Bs, acc);

  const int tid = threadIdx.x, wid = tid >> 6, lane = tid & 63;
  const int q = lane >> 4, ln = lane & 15;
  const int wr = wid >> 1, wc = wid & 1;
#pragma unroll
  for (int mt = 0; mt < 2; ++mt)
#pragma unroll
    for (int nt = 0; nt < 4; ++nt)
#pragma unroll
      for (int r = 0; r < 4; ++r) {
        const int d = bm * 64 + wr * 32 + mt * 16 + q * 4 + r;
        const int n = bn * 128 + wc * 64 + nt * 16 + ln;
        const int bb = n >> 11, l = n & 2047;
        out[((size_t)(bb * D + d)) * L + l] = acc[mt][nt][r];
      }
}

extern "C" void kernel_launch(void* const* d_in, const int* in_sizes, int n_in,
                              void* d_out, int out_size, void* d_ws,
                              size_t ws_size, hipStream_t stream) {
  const float* x    = (const float*)d_in[0];
  const float* mask = (const float*)d_in[1];
  const float* Wq   = (const float*)d_in[2];
  const float* Wk   = (const float*)d_in[3];
  const float* Wv   = (const float*)d_in[4];
  const float* Wo   = (const float*)d_in[5];
  u16* ws = (u16*)d_ws;
  u16* Qws  = ws;              // 4194304
  u16* Kws  = ws + 4194304;    // 4194304
  u16* Vtws = ws + 8388608;    // 4194304
  u16* WoTw = ws + 12582912;   // 1048576
  u16* Wtws = ws + 13631488;   // 3145728
  u16* xtws = ws + 16777216;   // 4194304 (xt dead after k_qkvg)
  u16* Hdws = ws + 16777216;   // alias of xt

  k_prep<<<2048, 256, 0, stream>>>(x, Wq, Wk, Wv, Wo, xtws, Wtws, WoTw);
  k_qkvg<<<dim3(32, 24), 256, 0, stream>>>(xtws, Wtws, Qws, Kws, Vtws);
  k_attn<<<dim3(16, 16, 2), 256, 0, stream>>>(Qws, Kws, Vtws, mask, Hdws);
  k_projg<<<dim3(16, 32), 256, 0, stream>>>(WoTw, Hdws, (float*)d_out);
}

// Round 15
// 214.632 us; speedup vs baseline: 1.1931x; 1.1931x over previous
//
#include <hip/hip_runtime.h>
#include <hip/hip_bf16.h>

typedef unsigned short u16;
typedef unsigned int u32;
typedef unsigned long long u64;
typedef short s8v __attribute__((ext_vector_type(8)));
typedef short s4v __attribute__((ext_vector_type(4)));
typedef __bf16 bfv8 __attribute__((ext_vector_type(8)));
typedef float f4 __attribute__((ext_vector_type(4)));

static constexpr int B = 2, D = 1024, L = 2048, H = 16, DK = 64, E = 1024;
// fold 1/sqrt(DK) and log2(e) into Q so softmax runs natively in exp2 domain
static constexpr float QSCALE = 0.125f * 1.44269504088896340736f;
static constexpr float SMB = -16.0f;       // fixed softmax bias (|s|<~10)
static constexpr float MASKB = -12000.0f;  // exp2(MASKB+s) == 0.0f exactly

#define DEV __device__ __forceinline__

DEV u16 f2bf(float f) {  // fp32 -> bf16 round-to-nearest-even
  unsigned int u = __float_as_uint(f);
  u += 0x7FFFu + ((u >> 16) & 1u);
  return (u16)(u >> 16);
}
DEV float fexp2(float x) { return __builtin_amdgcn_exp2f(x); }
DEV u32 pkbf(float a, float b) {  // packed fp32x2 -> bf16x2 (v_cvt_pk)
  __hip_bfloat162 h = __float22bfloat162_rn(float2{a, b});
  u32 r;
  __builtin_memcpy(&r, &h, 4);
  return r;
}

// K=16 bf16 MFMA (v_mfma_f32_16x16x16_bf16, 2 A / 2 B / 4 C regs).
DEV f4 mfma16(s4v a, s4v b, f4 c) {
  return __builtin_amdgcn_mfma_f32_16x16x16bf16_1k(a, b, c, 0, 0, 0);
}

#define GLD_LDS16(gp, lp)                                                     \
  __builtin_amdgcn_global_load_lds(                                           \
      (const __attribute__((address_space(1))) void*)(gp),                    \
      (__attribute__((address_space(3))) void*)(lp), 16, 0, 0)

// ---------- Kernel 0: fused fp32->bf16 64x64 tile transposes ----------
__global__ __launch_bounds__(256) void k_prep(
    const float* __restrict__ x, const float* __restrict__ Wq,
    const float* __restrict__ Wk, const float* __restrict__ Wv,
    const float* __restrict__ Wo, u16* __restrict__ xt, u16* __restrict__ Wt,
    u16* __restrict__ WoT) {
  __shared__ u16 t[64][67];
  const int tid = threadIdx.x;
  const int g = blockIdx.x;
  const float* src;
  u16* dst;
  int sld, dld;
  if (g < 1024) {
    const int b = g >> 9, dt = (g >> 5) & 15, lt = g & 31;
    src = x + ((size_t)b * D + dt * 64) * L + lt * 64;
    sld = L;
    dst = xt + ((size_t)b * L + lt * 64) * D + dt * 64;
    dld = D;
  } else if (g < 1792) {
    const int u = g - 1024;
    const int w = u >> 8, h = (u >> 4) & 15, dt = u & 15;
    const float* Ws = (w == 0) ? Wq : ((w == 1) ? Wk : Wv);
    src = Ws + ((size_t)h * D + dt * 64) * DK;
    sld = DK;
    dst = Wt + ((size_t)(w * H + h) * DK) * D + dt * 64;
    dld = D;
  } else {
    const int v = g - 1792;
    const int et = v >> 4, dt = v & 15;
    src = Wo + ((size_t)et * 64) * D + dt * 64;
    sld = D;
    dst = WoT + ((size_t)dt * 64) * E + et * 64;
    dld = E;
  }
  const int r = tid >> 2, c16 = (tid & 3) * 16;
#pragma unroll
  for (int j = 0; j < 16; j += 4) {
    const f4 v4 = *(const f4*)(src + (size_t)r * sld + c16 + j);
    t[r][c16 + j]     = f2bf(v4[0]);
    t[r][c16 + j + 1] = f2bf(v4[1]);
    t[r][c16 + j + 2] = f2bf(v4[2]);
    t[r][c16 + j + 3] = f2bf(v4[3]);
  }
  __syncthreads();
  s8v o0, o1;
#pragma unroll
  for (int i = 0; i < 8; ++i) {
    o0[i] = (short)t[c16 + i][r];
    o1[i] = (short)t[c16 + 8 + i][r];
  }
  *(s8v*)(dst + (size_t)r * dld + c16)     = o0;
  *(s8v*)(dst + (size_t)r * dld + c16 + 8) = o1;
}

// ---------- shared GEMM tile core: BK=64, single-buffer, 1 barrier-pair ----
// LDS tiles [rows][64] u16 (128B rows), swizzle phys_chunk = logical^(row&7).
template <int AR>
DEV void gemm_tile(const u16* __restrict__ A, const u16* __restrict__ Bt,
                   int arow0, int brow0, u16* As, u16* Bs,
                   f4 (&acc)[AR / 32][4]) {
  const int tid = threadIdx.x;
  const int wid = tid >> 6, lane = tid & 63;
  const int q = lane >> 4, ln = lane & 15;
  const int wr = wid >> 1, wc = wid & 1;
  const int lrow = lane >> 3;        // 0..7 (dest row & 7)
  const int lc = (lane & 7) ^ lrow;  // logical chunk for swizzled dest
  const int f0 = (q ^ (ln & 7)) * 8;        // frag phys chunk, k-step 0
  const int f1 = ((q + 4) ^ (ln & 7)) * 8;  // k-step 1
  constexpr int MT = AR / 32;

  for (int k0 = 0; k0 < 1024; k0 += 64) {
    __syncthreads();
#pragma unroll
    for (int j = 0; j < AR / 32; ++j) {  // A: 8 rows per instr
      const int rb = wid * (AR / 4) + j * 8;
      GLD_LDS16(A + (size_t)(arow0 + rb + lrow) * 1024 + k0 + lc * 8,
                As + rb * 64);
    }
#pragma unroll
    for (int j = 0; j < 4; ++j) {  // B: 128 rows
      const int rb = wid * 32 + j * 8;
      GLD_LDS16(Bt + (size_t)(brow0 + rb + lrow) * 1024 + k0 + lc * 8,
                Bs + rb * 64);
    }
    __syncthreads();
#pragma unroll
    for (int ks = 0; ks < 2; ++ks) {
      const int fc = ks ? f1 : f0;
      bfv8 af[MT], bf[4];
#pragma unroll
      for (int mt = 0; mt < MT; ++mt)
        af[mt] = *(const bfv8*)(As + (wr * (AR / 2) + mt * 16 + ln) * 64 + fc);
#pragma unroll
      for (int nt = 0; nt < 4; ++nt)
        bf[nt] = *(const bfv8*)(Bs + (wc * 64 + nt * 16 + ln) * 64 + fc);
#pragma unroll
      for (int mt = 0; mt < MT; ++mt)
#pragma unroll
        for (int nt = 0; nt < 4; ++nt)
          acc[mt][nt] = __builtin_amdgcn_mfma_f32_16x16x32_bf16(
              af[mt], bf[nt], acc[mt][nt], 0, 0, 0);
    }
  }
}

// ---------- Kernel 1: QKV projection as one GEMM ----------
__global__ __launch_bounds__(256, 3) void k_qkvg(
    const u16* __restrict__ xt, const u16* __restrict__ Wt,
    u16* __restrict__ Q, u16* __restrict__ K, u16* __restrict__ Vt) {
  __shared__ u16 As[128 * 64];  // 16 KB
  __shared__ u16 Bs[128 * 64];  // 16 KB  (32 KB total: 3 blocks/CU ok)
  const int bm = blockIdx.x, bn = blockIdx.y;
  f4 acc[4][4];
#pragma unroll
  for (int mt = 0; mt < 4; ++mt)
#pragma unroll
    for (int nt = 0; nt < 4; ++nt) acc[mt][nt] = (f4){0.f, 0.f, 0.f, 0.f};
  gemm_tile<128>(xt, Wt, bm * 128, bn * 128, As, Bs, acc);

  const int tid = threadIdx.x, wid = tid >> 6, lane = tid & 63;
  const int q = lane >> 4, ln = lane & 15;
  const int wr = wid >> 1, wc = wid & 1;
  const int h2 = bn * 2 + wc;  // 0..47
  const int wsel = h2 >> 4, h = h2 & 15;
  const int b = bm >> 4;
  const int lbase = (bm & 15) * 128 + wr * 64;
  if (wsel == 0) {
    u16* dst = Q + (size_t)(b * H + h) * L * DK;
#pragma unroll
    for (int mt = 0; mt < 4; ++mt)
#pragma unroll
      for (int nt = 0; nt < 4; ++nt)
#pragma unroll
        for (int r = 0; r < 4; ++r)
          dst[(size_t)(lbase + mt * 16 + q * 4 + r) * DK + nt * 16 + ln] =
              f2bf(acc[mt][nt][r] * QSCALE);
  } else if (wsel == 1) {
    u16* dst = K + (size_t)(b * H + h) * L * DK;
#pragma unroll
    for (int mt = 0; mt < 4; ++mt)
#pragma unroll
      for (int nt = 0; nt < 4; ++nt)
#pragma unroll
        for (int r = 0; r < 4; ++r)
          dst[(size_t)(lbase + mt * 16 + q * 4 + r) * DK + nt * 16 + ln] =
              f2bf(acc[mt][nt][r]);
  } else {
    // V: plain transpose Vt[dk][l], 4 consecutive l per lane -> 8B stores
    u16* dst = Vt + (size_t)(b * H + h) * DK * L;
#pragma unroll
    for (int mt = 0; mt < 4; ++mt)
#pragma unroll
      for (int nt = 0; nt < 4; ++nt) {
        const u64 pk = (u64)pkbf(acc[mt][nt][0], acc[mt][nt][1]) |
                       ((u64)pkbf(acc[mt][nt][2], acc[mt][nt][3]) << 32);
        *(u64*)(dst + (size_t)(nt * 16 + ln) * L + lbase + mt * 16 + q * 4) =
            pk;
      }
  }
}

// ---------- Kernel 2: flash attention, 3 blocks/CU ----------
// kt double-buffered (32 KB, single-barrier prefetch), vt single (16 KB)
// behind a second barrier AFTER the QK phase (gemm_tile-form, race-free:
// prev PV readers pass syncA before vt overwrite; vt drain slack = QK phase).
// Mask bias read direct from global fp32 (L2-hot, 8 KB). 48 KB total.
__global__ __launch_bounds__(256, 3) void k_attn(
    const u16* __restrict__ Q, const u16* __restrict__ K,
    const u16* __restrict__ Vt, const float* __restrict__ mask,
    u16* __restrict__ Hd) {
  __shared__ u16 kt[2][128 * 64];  // [key][dk], chunk-swizzled c^=(row&7)
  __shared__ u16 vt[2][64 * 64];   // [half][dk][key], single instance
  const int h = blockIdx.x, lt = blockIdx.y, b = blockIdx.z;
  const int tid = threadIdx.x;
  const int w = tid >> 6, lane = tid & 63, q = lane >> 4, ln = lane & 15;

  const int bh = b * H + h;
  const u16* Qp = Q + (size_t)bh * L * DK;
  const u16* Kp = K + (size_t)bh * L * DK;
  const u16* Vp = Vt + (size_t)bh * DK * L;
  const float* mp = mask + (size_t)b * L;
  const int lq = lt * 128 + w * 32;  // wave covers 32 q-rows

  bfv8 qf[2][2];
#pragma unroll
  for (int mt = 0; mt < 2; ++mt) {
    qf[mt][0] = *(const bfv8*)(Qp + (size_t)(lq + mt * 16 + ln) * DK + q * 8);
    qf[mt][1] =
        *(const bfv8*)(Qp + (size_t)(lq + mt * 16 + ln) * DK + 32 + q * 8);
  }

  const int lrow = lane >> 3;        // 0..7 (== dest row & 7)
  const int lc = (lane & 7) ^ lrow;  // logical chunk for swizzled dest
  const int fr0 = w * 16 + lrow, fr1 = fr0 + 8;  // V dk-rows
  const int c0 = (q ^ (ln & 7)) * 8;        // K-frag phys chunk, low dk half
  const int c1 = ((q + 4) ^ (ln & 7)) * 8;  // high dk half

  auto stageK = [&](int m0, int bufi) {  // key-rows [w*32, w*32+32)
#pragma unroll
    for (int j = 0; j < 4; ++j) {
      const int rb = w * 32 + j * 8;
      GLD_LDS16(Kp + (size_t)(m0 + rb + lrow) * DK + lc * 8,
                &kt[bufi][rb * 64]);
    }
  };
  auto stageV = [&](int m0) {  // two key-half planes, dk-rows [w*16,w*16+16)
#pragma unroll
    for (int kh = 0; kh < 2; ++kh) {
      GLD_LDS16(Vp + (size_t)fr0 * L + m0 + kh * 64 + lc * 8,
                &vt[kh][(w * 16) * 64]);
      GLD_LDS16(Vp + (size_t)fr1 * L + m0 + kh * 64 + lc * 8,
                &vt[kh][(w * 16 + 8) * 64]);
    }
  };

  f4 ot[2][4];  // O^T[dk=dt*16+q*4+r][qrow=mt*16+ln]
#pragma unroll
  for (int mt = 0; mt < 2; ++mt)
#pragma unroll
    for (int i = 0; i < 4; ++i) ot[mt][i] = (f4){0.f, 0.f, 0.f, 0.f};
  float lp[2] = {0.f, 0.f};  // partial row-sums (this quad's keys)

  stageK(0, 0);
  for (int it = 0; it < L / 128; ++it) {
    const int m0 = it * 128;
    __syncthreads();  // syncA: kt[it&1] landed; prev-iter vt reads done
    stageV(m0);       // single vt buffer — safe after syncA
    if (it + 1 < L / 128) stageK(m0 + 128, (it + 1) & 1);
    const u16* ktc = &kt[it & 1][0];

    // QK^T swapped (D[m=key][n=qrow]) fused with exp2+pack per 16-key strip
    s4v pb[2][8];
#pragma unroll
    for (int nt = 0; nt < 8; ++nt) {
      const int krow = nt * 16 + ln;  // krow&7 == ln&7: c0/c1 valid
      const bfv8 kf0 = *(const bfv8*)(ktc + krow * 64 + c0);
      const bfv8 kf1 = *(const bfv8*)(ktc + krow * 64 + c1);
      // mask bias from global fp32 (L2-hot), folded into accumulator init
      const f4 m4 = *(const f4*)(mp + m0 + nt * 16 + q * 4);
      f4 mbv;
#pragma unroll
      for (int i = 0; i < 4; ++i) mbv[i] = (m4[i] != 0.0f) ? SMB : MASKB;
#pragma unroll
      for (int mt = 0; mt < 2; ++mt) {
        f4 a = mbv;
        a = __builtin_amdgcn_mfma_f32_16x16x32_bf16(kf0, qf[mt][0], a, 0, 0,
                                                    0);
        a = __builtin_amdgcn_mfma_f32_16x16x32_bf16(kf1, qf[mt][1], a, 0, 0,
                                                    0);
        const float p0 = fexp2(a[0]);  // masked keys: exact 0
        const float p1 = fexp2(a[1]);
        const float p2 = fexp2(a[2]);
        const float p3 = fexp2(a[3]);
        lp[mt] += (p0 + p1) + (p2 + p3);
        const u64 pk = (u64)pkbf(p0, p1) | ((u64)pkbf(p2, p3) << 32);
        pb[mt][nt] = __builtin_bit_cast(s4v, pk);
      }
    }
    __syncthreads();  // syncB: vt landed (drain had the whole QK phase)

    // O^T += V^T . P^T  (V A-frags read once per (kh,dt,kc), 2 mt reuse)
#pragma unroll
    for (int kh = 0; kh < 2; ++kh) {
      const u16* vtc = &vt[kh][0];
#pragma unroll
      for (int dt = 0; dt < 4; ++dt) {
        const int vrow = dt * 16 + ln;
        const int vbase = vrow * 64 + (q & 1) * 4;
        const int rx = vrow & 7;
        s4v av[4];
#pragma unroll
        for (int kc = 0; kc < 4; ++kc)
          av[kc] =
              *(const s4v*)(vtc + vbase + (((kc * 2 + (q >> 1)) ^ rx) * 8));
#pragma unroll
        for (int kc = 0; kc < 4; ++kc)
#pragma unroll
          for (int mt = 0; mt < 2; ++mt)
            ot[mt][dt] = mfma16(av[kc], pb[mt][kh * 4 + kc], ot[mt][dt]);
      }
    }
  }
  // row-sum: reduce across the 4 quads (same qrow), normalize, store
#pragma unroll
  for (int mt = 0; mt < 2; ++mt) {
    lp[mt] += __shfl_xor(lp[mt], 16);
    lp[mt] += __shfl_xor(lp[mt], 32);
    const float qm = mp[lq + mt * 16 + ln];
    const float linv = (qm != 0.0f) ? (1.0f / lp[mt]) : 0.0f;
#pragma unroll
    for (int dt = 0; dt < 4; ++dt) {
      const u64 pk =
          (u64)pkbf(ot[mt][dt][0] * linv, ot[mt][dt][1] * linv) |
          ((u64)pkbf(ot[mt][dt][2] * linv, ot[mt][dt][3] * linv) << 32);
      *(u64*)(Hd + (size_t)(b * L + lq + mt * 16 + ln) * E + h * DK + dt * 16 +
              q * 4) = pk;
    }
  }
}

// ---------- Kernel 3: output projection as GEMM ----------
__global__ __launch_bounds__(256, 2) void k_projg(const u16* __restrict__ WoT,
                                                  const u16* __restrict__ Hd,
                                                  float* __restrict__ out) {
  __shared__ u16 As[64 * 64];   // 8 KB
  __shared__ u16 Bs[128 * 64];  // 16 KB
  const int bm = blockIdx.x, bn = blockIdx.y;
  f4 acc[2][4];
#pragma unroll
  for (int mt = 0; mt < 2; ++mt)
#pragma unroll
    for (int nt = 0; nt < 4; ++nt) acc[mt][nt] = (f4){0.f, 0.f, 0.f, 0.f};
  gemm_tile<64>(WoT, Hd, bm * 64, bn * 128, As, Bs, acc);

  const int tid = threadIdx.x, wid = tid >> 6, lane = tid & 63;
  const int q = lane >> 4, ln = lane & 15;
  const int wr = wid >> 1, wc = wid & 1;
#pragma unroll
  for (int mt = 0; mt < 2; ++mt)
#pragma unroll
    for (int nt = 0; nt < 4; ++nt)
#pragma unroll
      for (int r = 0; r < 4; ++r) {
        const int d = bm * 64 + wr * 32 + mt * 16 + q * 4 + r;
        const int n = bn * 128 + wc * 64 + nt * 16 + ln;
        const int bb = n >> 11, l = n & 2047;
        out[((size_t)(bb * D + d)) * L + l] = acc[mt][nt][r];
      }
}

extern "C" void kernel_launch(void* const* d_in, const int* in_sizes, int n_in,
                              void* d_out, int out_size, void* d_ws,
                              size_t ws_size, hipStream_t stream) {
  const float* x    = (const float*)d_in[0];
  const float* mask = (const float*)d_in[1];
  const float* Wq   = (const float*)d_in[2];
  const float* Wk   = (const float*)d_in[3];
  const float* Wv   = (const float*)d_in[4];
  const float* Wo   = (const float*)d_in[5];
  u16* ws = (u16*)d_ws;
  u16* Qws  = ws;              // 4194304
  u16* Kws  = ws + 4194304;    // 4194304
  u16* Vtws = ws + 8388608;    // 4194304
  u16* WoTw = ws + 12582912;   // 1048576
  u16* Wtws = ws + 13631488;   // 3145728
  u16* xtws = ws + 16777216;   // 4194304 (xt dead after k_qkvg)
  u16* Hdws = ws + 16777216;   // alias of xt

  k_prep<<<2048, 256, 0, stream>>>(x, Wq, Wk, Wv, Wo, xtws, Wtws, WoTw);
  k_qkvg<<<dim3(32, 24), 256, 0, stream>>>(xtws, Wtws, Qws, Kws, Vtws);
  k_attn<<<dim3(16, 16, 2), 256, 0, stream>>>(Qws, Kws, Vtws, mask, Hdws);
  k_projg<<<dim3(16, 32), 256, 0, stream>>>(WoTw, Hdws, (float*)d_out);
}

// Round 16
// 185.134 us; speedup vs baseline: 1.3831x; 1.1593x over previous
//
#include <hip/hip_runtime.h>
#include <hip/hip_bf16.h>

typedef unsigned short u16;
typedef unsigned int u32;
typedef unsigned long long u64;
typedef short s8v __attribute__((ext_vector_type(8)));
typedef short s4v __attribute__((ext_vector_type(4)));
typedef __bf16 bfv8 __attribute__((ext_vector_type(8)));
typedef float f4 __attribute__((ext_vector_type(4)));

static constexpr int B = 2, D = 1024, L = 2048, H = 16, DK = 64, E = 1024;
// fold 1/sqrt(DK) and log2(e) into Q so softmax runs natively in exp2 domain
static constexpr float QSCALE = 0.125f * 1.44269504088896340736f;
static constexpr float SMB = -16.0f;       // fixed softmax bias (|s|<~10)
static constexpr float MASKB = -12000.0f;  // exp2(MASKB+s) == 0.0f exactly

#define DEV __device__ __forceinline__

DEV u16 f2bf(float f) {  // fp32 -> bf16 round-to-nearest-even
  unsigned int u = __float_as_uint(f);
  u += 0x7FFFu + ((u >> 16) & 1u);
  return (u16)(u >> 16);
}
DEV float fexp2(float x) { return __builtin_amdgcn_exp2f(x); }
DEV u32 pkbf(float a, float b) {  // packed fp32x2 -> bf16x2 (v_cvt_pk)
  __hip_bfloat162 h = __float22bfloat162_rn(float2{a, b});
  u32 r;
  __builtin_memcpy(&r, &h, 4);
  return r;
}

// K=16 bf16 MFMA (v_mfma_f32_16x16x16_bf16, 2 A / 2 B / 4 C regs).
DEV f4 mfma16(s4v a, s4v b, f4 c) {
  return __builtin_amdgcn_mfma_f32_16x16x16bf16_1k(a, b, c, 0, 0, 0);
}

#define GLD_LDS16(gp, lp)                                                     \
  __builtin_amdgcn_global_load_lds(                                           \
      (const __attribute__((address_space(1))) void*)(gp),                    \
      (__attribute__((address_space(3))) void*)(lp), 16, 0, 0)

// ---------- Kernel 0: fused fp32->bf16 64x64 tile transposes ----------
__global__ __launch_bounds__(256) void k_prep(
    const float* __restrict__ x, const float* __restrict__ Wq,
    const float* __restrict__ Wk, const float* __restrict__ Wv,
    const float* __restrict__ Wo, u16* __restrict__ xt, u16* __restrict__ Wt,
    u16* __restrict__ WoT) {
  __shared__ u16 t[64][67];
  const int tid = threadIdx.x;
  const int g = blockIdx.x;
  const float* src;
  u16* dst;
  int sld, dld;
  if (g < 1024) {
    const int b = g >> 9, dt = (g >> 5) & 15, lt = g & 31;
    src = x + ((size_t)b * D + dt * 64) * L + lt * 64;
    sld = L;
    dst = xt + ((size_t)b * L + lt * 64) * D + dt * 64;
    dld = D;
  } else if (g < 1792) {
    const int u = g - 1024;
    const int w = u >> 8, h = (u >> 4) & 15, dt = u & 15;
    const float* Ws = (w == 0) ? Wq : ((w == 1) ? Wk : Wv);
    src = Ws + ((size_t)h * D + dt * 64) * DK;
    sld = DK;
    dst = Wt + ((size_t)(w * H + h) * DK) * D + dt * 64;
    dld = D;
  } else {
    const int v = g - 1792;
    const int et = v >> 4, dt = v & 15;
    src = Wo + ((size_t)et * 64) * D + dt * 64;
    sld = D;
    dst = WoT + ((size_t)dt * 64) * E + et * 64;
    dld = E;
  }
  const int r = tid >> 2, c16 = (tid & 3) * 16;
#pragma unroll
  for (int j = 0; j < 16; j += 4) {
    const f4 v4 = *(const f4*)(src + (size_t)r * sld + c16 + j);
    t[r][c16 + j]     = f2bf(v4[0]);
    t[r][c16 + j + 1] = f2bf(v4[1]);
    t[r][c16 + j + 2] = f2bf(v4[2]);
    t[r][c16 + j + 3] = f2bf(v4[3]);
  }
  __syncthreads();
  s8v o0, o1;
#pragma unroll
  for (int i = 0; i < 8; ++i) {
    o0[i] = (short)t[c16 + i][r];
    o1[i] = (short)t[c16 + 8 + i][r];
  }
  *(s8v*)(dst + (size_t)r * dld + c16)     = o0;
  *(s8v*)(dst + (size_t)r * dld + c16 + 8) = o1;
}

// ---------- shared GEMM tile core: BK=64, single-buffer, 1 barrier-pair ----
// LDS tiles [rows][64] u16 (128B rows), swizzle phys_chunk = logical^(row&7).
template <int AR>
DEV void gemm_tile(const u16* __restrict__ A, const u16* __restrict__ Bt,
                   int arow0, int brow0, u16* As, u16* Bs,
                   f4 (&acc)[AR / 32][4]) {
  const int tid = threadIdx.x;
  const int wid = tid >> 6, lane = tid & 63;
  const int q = lane >> 4, ln = lane & 15;
  const int wr = wid >> 1, wc = wid & 1;
  const int lrow = lane >> 3;        // 0..7 (dest row & 7)
  const int lc = (lane & 7) ^ lrow;  // logical chunk for swizzled dest
  const int f0 = (q ^ (ln & 7)) * 8;        // frag phys chunk, k-step 0
  const int f1 = ((q + 4) ^ (ln & 7)) * 8;  // k-step 1
  constexpr int MT = AR / 32;

  for (int k0 = 0; k0 < 1024; k0 += 64) {
    __syncthreads();
#pragma unroll
    for (int j = 0; j < AR / 32; ++j) {  // A: 8 rows per instr
      const int rb = wid * (AR / 4) + j * 8;
      GLD_LDS16(A + (size_t)(arow0 + rb + lrow) * 1024 + k0 + lc * 8,
                As + rb * 64);
    }
#pragma unroll
    for (int j = 0; j < 4; ++j) {  // B: 128 rows
      const int rb = wid * 32 + j * 8;
      GLD_LDS16(Bt + (size_t)(brow0 + rb + lrow) * 1024 + k0 + lc * 8,
                Bs + rb * 64);
    }
    __syncthreads();
#pragma unroll
    for (int ks = 0; ks < 2; ++ks) {
      const int fc = ks ? f1 : f0;
      bfv8 af[MT], bf[4];
#pragma unroll
      for (int mt = 0; mt < MT; ++mt)
        af[mt] = *(const bfv8*)(As + (wr * (AR / 2) + mt * 16 + ln) * 64 + fc);
#pragma unroll
      for (int nt = 0; nt < 4; ++nt)
        bf[nt] = *(const bfv8*)(Bs + (wc * 64 + nt * 16 + ln) * 64 + fc);
#pragma unroll
      for (int mt = 0; mt < MT; ++mt)
#pragma unroll
        for (int nt = 0; nt < 4; ++nt)
          acc[mt][nt] = __builtin_amdgcn_mfma_f32_16x16x32_bf16(
              af[mt], bf[nt], acc[mt][nt], 0, 0, 0);
    }
  }
}

// ---------- Kernel 1: QKV projection as one GEMM ----------
__global__ __launch_bounds__(256, 3) void k_qkvg(
    const u16* __restrict__ xt, const u16* __restrict__ Wt,
    u16* __restrict__ Q, u16* __restrict__ K, u16* __restrict__ Vt) {
  __shared__ u16 As[128 * 64];  // 16 KB
  __shared__ u16 Bs[128 * 64];  // 16 KB  (32 KB total: 3 blocks/CU ok)
  const int bm = blockIdx.x, bn = blockIdx.y;
  f4 acc[4][4];
#pragma unroll
  for (int mt = 0; mt < 4; ++mt)
#pragma unroll
    for (int nt = 0; nt < 4; ++nt) acc[mt][nt] = (f4){0.f, 0.f, 0.f, 0.f};
  gemm_tile<128>(xt, Wt, bm * 128, bn * 128, As, Bs, acc);

  const int tid = threadIdx.x, wid = tid >> 6, lane = tid & 63;
  const int q = lane >> 4, ln = lane & 15;
  const int wr = wid >> 1, wc = wid & 1;
  const int h2 = bn * 2 + wc;  // 0..47
  const int wsel = h2 >> 4, h = h2 & 15;
  const int b = bm >> 4;
  const int lbase = (bm & 15) * 128 + wr * 64;
  if (wsel == 0) {
    u16* dst = Q + (size_t)(b * H + h) * L * DK;
#pragma unroll
    for (int mt = 0; mt < 4; ++mt)
#pragma unroll
      for (int nt = 0; nt < 4; ++nt)
#pragma unroll
        for (int r = 0; r < 4; ++r)
          dst[(size_t)(lbase + mt * 16 + q * 4 + r) * DK + nt * 16 + ln] =
              f2bf(acc[mt][nt][r] * QSCALE);
  } else if (wsel == 1) {
    u16* dst = K + (size_t)(b * H + h) * L * DK;
#pragma unroll
    for (int mt = 0; mt < 4; ++mt)
#pragma unroll
      for (int nt = 0; nt < 4; ++nt)
#pragma unroll
        for (int r = 0; r < 4; ++r)
          dst[(size_t)(lbase + mt * 16 + q * 4 + r) * DK + nt * 16 + ln] =
              f2bf(acc[mt][nt][r]);
  } else {
    // V: plain transpose Vt[dk][l], 4 consecutive l per lane -> 8B stores
    u16* dst = Vt + (size_t)(b * H + h) * DK * L;
#pragma unroll
    for (int mt = 0; mt < 4; ++mt)
#pragma unroll
      for (int nt = 0; nt < 4; ++nt) {
        const u64 pk = (u64)pkbf(acc[mt][nt][0], acc[mt][nt][1]) |
                       ((u64)pkbf(acc[mt][nt][2], acc[mt][nt][3]) << 32);
        *(u64*)(dst + (size_t)(nt * 16 + ln) * L + lbase + mt * 16 + q * 4) =
            pk;
      }
  }
}

// ---------- Kernel 2: flash attention, 128-key tiles (R12 known-good) ------
// Single barrier per tile; K tile + two V planes double-buffered; in-register
// P (operand-swapped QK^T -> PV B-frags); 32 q-rows/wave; 2 blocks/CU.
__global__ __launch_bounds__(256, 2) void k_attn(
    const u16* __restrict__ Q, const u16* __restrict__ K,
    const u16* __restrict__ Vt, const float* __restrict__ mask,
    u16* __restrict__ Hd) {
  __shared__ u16 kt[2][128 * 64];    // [key][dk], chunk-swizzled c^=(row&7)
  __shared__ u16 vt[2][2][64 * 64];  // [half][dk][key], same swizzle
  __shared__ __align__(16) float mb[L];  // per-key bias: SMB or MASKB
  const int h = blockIdx.x, lt = blockIdx.y, b = blockIdx.z;
  const int tid = threadIdx.x;
  const int w = tid >> 6, lane = tid & 63, q = lane >> 4, ln = lane & 15;
  for (int i = tid; i < L; i += 256)
    mb[i] = (mask[(size_t)b * L + i] != 0.0f) ? SMB : MASKB;

  const int bh = b * H + h;
  const u16* Qp = Q + (size_t)bh * L * DK;
  const u16* Kp = K + (size_t)bh * L * DK;
  const u16* Vp = Vt + (size_t)bh * DK * L;
  const int lq = lt * 128 + w * 32;  // wave covers 32 q-rows

  bfv8 qf[2][2];
#pragma unroll
  for (int mt = 0; mt < 2; ++mt) {
    qf[mt][0] = *(const bfv8*)(Qp + (size_t)(lq + mt * 16 + ln) * DK + q * 8);
    qf[mt][1] =
        *(const bfv8*)(Qp + (size_t)(lq + mt * 16 + ln) * DK + 32 + q * 8);
  }

  const int lrow = lane >> 3;        // 0..7 (== dest row & 7)
  const int lc = (lane & 7) ^ lrow;  // logical chunk for swizzled dest
  const int fr0 = w * 16 + lrow, fr1 = fr0 + 8;  // V dk-rows
  const int c0 = (q ^ (ln & 7)) * 8;        // K-frag phys chunk, low dk half
  const int c1 = ((q + 4) ^ (ln & 7)) * 8;  // high dk half

  auto stage = [&](int m0, int bufi) {
#pragma unroll
    for (int j = 0; j < 4; ++j) {
      const int rb = w * 32 + j * 8;
      GLD_LDS16(Kp + (size_t)(m0 + rb + lrow) * DK + lc * 8,
                &kt[bufi][rb * 64]);
    }
#pragma unroll
    for (int kh = 0; kh < 2; ++kh) {
      GLD_LDS16(Vp + (size_t)fr0 * L + m0 + kh * 64 + lc * 8,
                &vt[bufi][kh][(w * 16) * 64]);
      GLD_LDS16(Vp + (size_t)fr1 * L + m0 + kh * 64 + lc * 8,
                &vt[bufi][kh][(w * 16 + 8) * 64]);
    }
  };

  f4 ot[2][4];  // O^T[dk=dt*16+q*4+r][qrow=mt*16+ln]
#pragma unroll
  for (int mt = 0; mt < 2; ++mt)
#pragma unroll
    for (int i = 0; i < 4; ++i) ot[mt][i] = (f4){0.f, 0.f, 0.f, 0.f};
  float lp[2] = {0.f, 0.f};  // partial row-sums (this quad's keys)

  stage(0, 0);
  for (int it = 0; it < L / 128; ++it) {
    const int m0 = it * 128;
    __syncthreads();  // buf(it&1) landed; mb ready; prev buf reads done
    if (it + 1 < L / 128) stage(m0 + 128, (it + 1) & 1);
    const int cur = it & 1;
    const u16* ktc = &kt[cur][0];

    // QK^T swapped (D[m=key][n=qrow]) fused with exp2+pack per 16-key strip
    s4v pb[2][8];
#pragma unroll
    for (int nt = 0; nt < 8; ++nt) {
      const int krow = nt * 16 + ln;  // krow&7 == ln&7: c0/c1 valid
      const bfv8 kf0 = *(const bfv8*)(ktc + krow * 64 + c0);
      const bfv8 kf1 = *(const bfv8*)(ktc + krow * 64 + c1);
      const f4 mbv = *(const f4*)(mb + m0 + nt * 16 + q * 4);
#pragma unroll
      for (int mt = 0; mt < 2; ++mt) {
        f4 a = mbv;  // mask bias in accumulator init
        a = __builtin_amdgcn_mfma_f32_16x16x32_bf16(kf0, qf[mt][0], a, 0, 0,
                                                    0);
        a = __builtin_amdgcn_mfma_f32_16x16x32_bf16(kf1, qf[mt][1], a, 0, 0,
                                                    0);
        const float p0 = fexp2(a[0]);  // masked keys: exact 0
        const float p1 = fexp2(a[1]);
        const float p2 = fexp2(a[2]);
        const float p3 = fexp2(a[3]);
        lp[mt] += (p0 + p1) + (p2 + p3);
        const u64 pk = (u64)pkbf(p0, p1) | ((u64)pkbf(p2, p3) << 32);
        pb[mt][nt] = __builtin_bit_cast(s4v, pk);
      }
    }
    // O^T += V^T . P^T  (V A-frags read once per (kh,dt,kc), 2 mt reuse)
#pragma unroll
    for (int kh = 0; kh < 2; ++kh) {
      const u16* vtc = &vt[cur][kh][0];
#pragma unroll
      for (int dt = 0; dt < 4; ++dt) {
        const int vrow = dt * 16 + ln;
        const int vbase = vrow * 64 + (q & 1) * 4;
        const int rx = vrow & 7;
        s4v av[4];
#pragma unroll
        for (int kc = 0; kc < 4; ++kc)
          av[kc] =
              *(const s4v*)(vtc + vbase + (((kc * 2 + (q >> 1)) ^ rx) * 8));
#pragma unroll
        for (int kc = 0; kc < 4; ++kc)
#pragma unroll
          for (int mt = 0; mt < 2; ++mt)
            ot[mt][dt] = mfma16(av[kc], pb[mt][kh * 4 + kc], ot[mt][dt]);
      }
    }
  }
  // row-sum: reduce across the 4 quads (same qrow), normalize, store
#pragma unroll
  for (int mt = 0; mt < 2; ++mt) {
    lp[mt] += __shfl_xor(lp[mt], 16);
    lp[mt] += __shfl_xor(lp[mt], 32);
    const float linv =
        (mb[lq + mt * 16 + ln] > -100.0f) ? (1.0f / lp[mt]) : 0.0f;
#pragma unroll
    for (int dt = 0; dt < 4; ++dt) {
      const u64 pk =
          (u64)pkbf(ot[mt][dt][0] * linv, ot[mt][dt][1] * linv) |
          ((u64)pkbf(ot[mt][dt][2] * linv, ot[mt][dt][3] * linv) << 32);
      *(u64*)(Hd + (size_t)(b * L + lq + mt * 16 + ln) * E + h * DK + dt * 16 +
              q * 4) = pk;
    }
  }
}

// ---------- Kernel 3: output projection as GEMM ----------
__global__ __launch_bounds__(256, 2) void k_projg(const u16* __restrict__ WoT,
                                                  const u16* __restrict__ Hd,
                                                  float* __restrict__ out) {
  __shared__ u16 As[64 * 64];   // 8 KB
  __shared__ u16 Bs[128 * 64];  // 16 KB
  const int bm = blockIdx.x, bn = blockIdx.y;
  f4 acc[2][4];
#pragma unroll
  for (int mt = 0; mt < 2; ++mt)
#pragma unroll
    for (int nt = 0; nt < 4; ++nt) acc[mt][nt] = (f4){0.f, 0.f, 0.f, 0.f};
  gemm_tile<64>(WoT, Hd, bm * 64, bn * 128, As, Bs, acc);

  const int tid = threadIdx.x, wid = tid >> 6, lane = tid & 63;
  const int q = lane >> 4, ln = lane & 15;
  const int wr = wid >> 1, wc = wid & 1;
#pragma unroll
  for (int mt = 0; mt < 2; ++mt)
#pragma unroll
    for (int nt = 0; nt < 4; ++nt)
#pragma unroll
      for (int r = 0; r < 4; ++r) {
        const int d = bm * 64 + wr * 32 + mt * 16 + q * 4 + r;
        const int n = bn * 128 + wc * 64 + nt * 16 + ln;
        const int bb = n >> 11, l = n & 2047;
        out[((size_t)(bb * D + d)) * L + l] = acc[mt][nt][r];
      }
}

extern "C" void kernel_launch(void* const* d_in, const int* in_sizes, int n_in,
                              void* d_out, int out_size, void* d_ws,
                              size_t ws_size, hipStream_t stream) {
  const float* x    = (const float*)d_in[0];
  const float* mask = (const float*)d_in[1];
  const float* Wq   = (const float*)d_in[2];
  const float* Wk   = (const float*)d_in[3];
  const float* Wv   = (const float*)d_in[4];
  const float* Wo   = (const float*)d_in[5];
  u16* ws = (u16*)d_ws;
  u16* Qws  = ws;              // 4194304
  u16* Kws  = ws + 4194304;    // 4194304
  u16* Vtws = ws + 8388608;    // 4194304
  u16* WoTw = ws + 12582912;   // 1048576
  u16* Wtws = ws + 13631488;   // 3145728
  u16* xtws = ws + 16777216;   // 4194304 (xt dead after k_qkvg)
  u16* Hdws = ws + 16777216;   // alias of xt

  k_prep<<<2048, 256, 0, stream>>>(x, Wq, Wk, Wv, Wo, xtws, Wtws, WoTw);
  k_qkvg<<<dim3(32, 24), 256, 0, stream>>>(xtws, Wtws, Qws, Kws, Vtws);
  k_attn<<<dim3(16, 16, 2), 256, 0, stream>>>(Qws, Kws, Vtws, mask, Hdws);
  k_projg<<<dim3(16, 32), 256, 0, stream>>>(WoTw, Hdws, (float*)d_out);
}

// Round 17
// 177.344 us; speedup vs baseline: 1.4439x; 1.0439x over previous
//
#include <hip/hip_runtime.h>
#include <hip/hip_bf16.h>

typedef unsigned short u16;
typedef unsigned int u32;
typedef unsigned long long u64;
typedef short s8v __attribute__((ext_vector_type(8)));
typedef short s4v __attribute__((ext_vector_type(4)));
typedef __bf16 bfv8 __attribute__((ext_vector_type(8)));
typedef float f4 __attribute__((ext_vector_type(4)));

static constexpr int B = 2, D = 1024, L = 2048, H = 16, DK = 64, E = 1024;
// fold 1/sqrt(DK) and log2(e) into Q so softmax runs natively in exp2 domain
static constexpr float QSCALE = 0.125f * 1.44269504088896340736f;
static constexpr float SMB = -16.0f;       // fixed softmax bias (|s|<~10)
static constexpr float MASKB = -12000.0f;  // exp2(MASKB+s) == 0.0f exactly

#define DEV __device__ __forceinline__

DEV u16 f2bf(float f) {  // fp32 -> bf16 round-to-nearest-even
  unsigned int u = __float_as_uint(f);
  u += 0x7FFFu + ((u >> 16) & 1u);
  return (u16)(u >> 16);
}
DEV float fexp2(float x) { return __builtin_amdgcn_exp2f(x); }
DEV u32 pkbf(float a, float b) {  // packed fp32x2 -> bf16x2 (v_cvt_pk)
  __hip_bfloat162 h = __float22bfloat162_rn(float2{a, b});
  u32 r;
  __builtin_memcpy(&r, &h, 4);
  return r;
}

// K=16 bf16 MFMA (v_mfma_f32_16x16x16_bf16, 2 A / 2 B / 4 C regs).
DEV f4 mfma16(s4v a, s4v b, f4 c) {
  return __builtin_amdgcn_mfma_f32_16x16x16bf16_1k(a, b, c, 0, 0, 0);
}

#define GLD_LDS16(gp, lp)                                                     \
  __builtin_amdgcn_global_load_lds(                                           \
      (const __attribute__((address_space(1))) void*)(gp),                    \
      (__attribute__((address_space(3))) void*)(lp), 16, 0, 0)

// ---------- Kernel 0: fused fp32->bf16 64x64 tile transposes ----------
// Stride 66 (even): u32-aligned packed row writes; column reads 2-way
// bank-aliased (free per m136).
__global__ __launch_bounds__(256) void k_prep(
    const float* __restrict__ x, const float* __restrict__ Wq,
    const float* __restrict__ Wk, const float* __restrict__ Wv,
    const float* __restrict__ Wo, u16* __restrict__ xt, u16* __restrict__ Wt,
    u16* __restrict__ WoT) {
  __shared__ __align__(16) u16 t[64][66];
  const int tid = threadIdx.x;
  const int g = blockIdx.x;
  const float* src;
  u16* dst;
  int sld, dld;
  if (g < 1024) {
    const int b = g >> 9, dt = (g >> 5) & 15, lt = g & 31;
    src = x + ((size_t)b * D + dt * 64) * L + lt * 64;
    sld = L;
    dst = xt + ((size_t)b * L + lt * 64) * D + dt * 64;
    dld = D;
  } else if (g < 1792) {
    const int u = g - 1024;
    const int w = u >> 8, h = (u >> 4) & 15, dt = u & 15;
    const float* Ws = (w == 0) ? Wq : ((w == 1) ? Wk : Wv);
    src = Ws + ((size_t)h * D + dt * 64) * DK;
    sld = DK;
    dst = Wt + ((size_t)(w * H + h) * DK) * D + dt * 64;
    dld = D;
  } else {
    const int v = g - 1792;
    const int et = v >> 4, dt = v & 15;
    src = Wo + ((size_t)et * 64) * D + dt * 64;
    sld = D;
    dst = WoT + ((size_t)dt * 64) * E + et * 64;
    dld = E;
  }
  const int r = tid >> 2, c16 = (tid & 3) * 16;
#pragma unroll
  for (int j = 0; j < 16; j += 4) {
    const f4 v4 = *(const f4*)(src + (size_t)r * sld + c16 + j);
    *(u32*)&t[r][c16 + j]     = pkbf(v4[0], v4[1]);  // packed cvt + u32 store
    *(u32*)&t[r][c16 + j + 2] = pkbf(v4[2], v4[3]);
  }
  __syncthreads();
  s8v o0, o1;
#pragma unroll
  for (int i = 0; i < 8; ++i) {
    o0[i] = (short)t[c16 + i][r];
    o1[i] = (short)t[c16 + 8 + i][r];
  }
  *(s8v*)(dst + (size_t)r * dld + c16)     = o0;
  *(s8v*)(dst + (size_t)r * dld + c16 + 8) = o1;
}

// ---------- shared GEMM tile core: BK=64, single-buffer, 1 barrier-pair ----
// LDS tiles [rows][64] u16 (128B rows), swizzle phys_chunk = logical^(row&7).
template <int AR>
DEV void gemm_tile(const u16* __restrict__ A, const u16* __restrict__ Bt,
                   int arow0, int brow0, u16* As, u16* Bs,
                   f4 (&acc)[AR / 32][4]) {
  const int tid = threadIdx.x;
  const int wid = tid >> 6, lane = tid & 63;
  const int q = lane >> 4, ln = lane & 15;
  const int wr = wid >> 1, wc = wid & 1;
  const int lrow = lane >> 3;        // 0..7 (dest row & 7)
  const int lc = (lane & 7) ^ lrow;  // logical chunk for swizzled dest
  const int f0 = (q ^ (ln & 7)) * 8;        // frag phys chunk, k-step 0
  const int f1 = ((q + 4) ^ (ln & 7)) * 8;  // k-step 1
  constexpr int MT = AR / 32;

  for (int k0 = 0; k0 < 1024; k0 += 64) {
    __syncthreads();
#pragma unroll
    for (int j = 0; j < AR / 32; ++j) {  // A: 8 rows per instr
      const int rb = wid * (AR / 4) + j * 8;
      GLD_LDS16(A + (size_t)(arow0 + rb + lrow) * 1024 + k0 + lc * 8,
                As + rb * 64);
    }
#pragma unroll
    for (int j = 0; j < 4; ++j) {  // B: 128 rows
      const int rb = wid * 32 + j * 8;
      GLD_LDS16(Bt + (size_t)(brow0 + rb + lrow) * 1024 + k0 + lc * 8,
                Bs + rb * 64);
    }
    __syncthreads();
#pragma unroll
    for (int ks = 0; ks < 2; ++ks) {
      const int fc = ks ? f1 : f0;
      bfv8 af[MT], bf[4];
#pragma unroll
      for (int mt = 0; mt < MT; ++mt)
        af[mt] = *(const bfv8*)(As + (wr * (AR / 2) + mt * 16 + ln) * 64 + fc);
#pragma unroll
      for (int nt = 0; nt < 4; ++nt)
        bf[nt] = *(const bfv8*)(Bs + (wc * 64 + nt * 16 + ln) * 64 + fc);
#pragma unroll
      for (int mt = 0; mt < MT; ++mt)
#pragma unroll
        for (int nt = 0; nt < 4; ++nt)
          acc[mt][nt] = __builtin_amdgcn_mfma_f32_16x16x32_bf16(
              af[mt], bf[nt], acc[mt][nt], 0, 0, 0);
    }
  }
}

// ---------- Kernel 1: QKV projection as one GEMM ----------
__global__ __launch_bounds__(256, 3) void k_qkvg(
    const u16* __restrict__ xt, const u16* __restrict__ Wt,
    u16* __restrict__ Q, u16* __restrict__ K, u16* __restrict__ Vt) {
  __shared__ u16 As[128 * 64];  // 16 KB
  __shared__ u16 Bs[128 * 64];  // 16 KB  (32 KB total: 3 blocks/CU ok)
  const int bm = blockIdx.x, bn = blockIdx.y;
  f4 acc[4][4];
#pragma unroll
  for (int mt = 0; mt < 4; ++mt)
#pragma unroll
    for (int nt = 0; nt < 4; ++nt) acc[mt][nt] = (f4){0.f, 0.f, 0.f, 0.f};
  gemm_tile<128>(xt, Wt, bm * 128, bn * 128, As, Bs, acc);

  const int tid = threadIdx.x, wid = tid >> 6, lane = tid & 63;
  const int q = lane >> 4, ln = lane & 15;
  const int wr = wid >> 1, wc = wid & 1;
  const int h2 = bn * 2 + wc;  // 0..47
  const int wsel = h2 >> 4, h = h2 & 15;
  const int b = bm >> 4;
  const int lbase = (bm & 15) * 128 + wr * 64;
  if (wsel == 0) {
    u16* dst = Q + (size_t)(b * H + h) * L * DK;
#pragma unroll
    for (int mt = 0; mt < 4; ++mt)
#pragma unroll
      for (int nt = 0; nt < 4; ++nt)
#pragma unroll
        for (int r = 0; r < 4; ++r)
          dst[(size_t)(lbase + mt * 16 + q * 4 + r) * DK + nt * 16 + ln] =
              f2bf(acc[mt][nt][r] * QSCALE);
  } else if (wsel == 1) {
    u16* dst = K + (size_t)(b * H + h) * L * DK;
#pragma unroll
    for (int mt = 0; mt < 4; ++mt)
#pragma unroll
      for (int nt = 0; nt < 4; ++nt)
#pragma unroll
        for (int r = 0; r < 4; ++r)
          dst[(size_t)(lbase + mt * 16 + q * 4 + r) * DK + nt * 16 + ln] =
              f2bf(acc[mt][nt][r]);
  } else {
    // V: plain transpose Vt[dk][l], 4 consecutive l per lane -> 8B stores
    u16* dst = Vt + (size_t)(b * H + h) * DK * L;
#pragma unroll
    for (int mt = 0; mt < 4; ++mt)
#pragma unroll
      for (int nt = 0; nt < 4; ++nt) {
        const u64 pk = (u64)pkbf(acc[mt][nt][0], acc[mt][nt][1]) |
                       ((u64)pkbf(acc[mt][nt][2], acc[mt][nt][3]) << 32);
        *(u64*)(dst + (size_t)(nt * 16 + ln) * L + lbase + mt * 16 + q * 4) =
            pk;
      }
  }
}

// ---------- Kernel 2: flash attention, 128-key tiles (R12 known-good) ------
// Single barrier per tile; K tile + two V planes double-buffered; in-register
// P (operand-swapped QK^T -> PV B-frags); 32 q-rows/wave; 2 blocks/CU.
__global__ __launch_bounds__(256, 2) void k_attn(
    const u16* __restrict__ Q, const u16* __restrict__ K,
    const u16* __restrict__ Vt, const float* __restrict__ mask,
    u16* __restrict__ Hd) {
  __shared__ u16 kt[2][128 * 64];    // [key][dk], chunk-swizzled c^=(row&7)
  __shared__ u16 vt[2][2][64 * 64];  // [half][dk][key], same swizzle
  __shared__ __align__(16) float mb[L];  // per-key bias: SMB or MASKB
  const int h = blockIdx.x, lt = blockIdx.y, b = blockIdx.z;
  const int tid = threadIdx.x;
  const int w = tid >> 6, lane = tid & 63, q = lane >> 4, ln = lane & 15;
  for (int i = tid; i < L; i += 256)
    mb[i] = (mask[(size_t)b * L + i] != 0.0f) ? SMB : MASKB;

  const int bh = b * H + h;
  const u16* Qp = Q + (size_t)bh * L * DK;
  const u16* Kp = K + (size_t)bh * L * DK;
  const u16* Vp = Vt + (size_t)bh * DK * L;
  const int lq = lt * 128 + w * 32;  // wave covers 32 q-rows

  bfv8 qf[2][2];
#pragma unroll
  for (int mt = 0; mt < 2; ++mt) {
    qf[mt][0] = *(const bfv8*)(Qp + (size_t)(lq + mt * 16 + ln) * DK + q * 8);
    qf[mt][1] =
        *(const bfv8*)(Qp + (size_t)(lq + mt * 16 + ln) * DK + 32 + q * 8);
  }

  const int lrow = lane >> 3;        // 0..7 (== dest row & 7)
  const int lc = (lane & 7) ^ lrow;  // logical chunk for swizzled dest
  const int fr0 = w * 16 + lrow, fr1 = fr0 + 8;  // V dk-rows
  const int c0 = (q ^ (ln & 7)) * 8;        // K-frag phys chunk, low dk half
  const int c1 = ((q + 4) ^ (ln & 7)) * 8;  // high dk half

  auto stage = [&](int m0, int bufi) {
#pragma unroll
    for (int j = 0; j < 4; ++j) {
      const int rb = w * 32 + j * 8;
      GLD_LDS16(Kp + (size_t)(m0 + rb + lrow) * DK + lc * 8,
                &kt[bufi][rb * 64]);
    }
#pragma unroll
    for (int kh = 0; kh < 2; ++kh) {
      GLD_LDS16(Vp + (size_t)fr0 * L + m0 + kh * 64 + lc * 8,
                &vt[bufi][kh][(w * 16) * 64]);
      GLD_LDS16(Vp + (size_t)fr1 * L + m0 + kh * 64 + lc * 8,
                &vt[bufi][kh][(w * 16 + 8) * 64]);
    }
  };

  f4 ot[2][4];  // O^T[dk=dt*16+q*4+r][qrow=mt*16+ln]
#pragma unroll
  for (int mt = 0; mt < 2; ++mt)
#pragma unroll
    for (int i = 0; i < 4; ++i) ot[mt][i] = (f4){0.f, 0.f, 0.f, 0.f};
  float lp[2] = {0.f, 0.f};  // partial row-sums (this quad's keys)

  stage(0, 0);
  for (int it = 0; it < L / 128; ++it) {
    const int m0 = it * 128;
    __syncthreads();  // buf(it&1) landed; mb ready; prev buf reads done
    if (it + 1 < L / 128) stage(m0 + 128, (it + 1) & 1);
    const int cur = it & 1;
    const u16* ktc = &kt[cur][0];

    // QK^T swapped (D[m=key][n=qrow]) fused with exp2+pack per 16-key strip
    s4v pb[2][8];
#pragma unroll
    for (int nt = 0; nt < 8; ++nt) {
      const int krow = nt * 16 + ln;  // krow&7 == ln&7: c0/c1 valid
      const bfv8 kf0 = *(const bfv8*)(ktc + krow * 64 + c0);
      const bfv8 kf1 = *(const bfv8*)(ktc + krow * 64 + c1);
      const f4 mbv = *(const f4*)(mb + m0 + nt * 16 + q * 4);
#pragma unroll
      for (int mt = 0; mt < 2; ++mt) {
        f4 a = mbv;  // mask bias in accumulator init
        a = __builtin_amdgcn_mfma_f32_16x16x32_bf16(kf0, qf[mt][0], a, 0, 0,
                                                    0);
        a = __builtin_amdgcn_mfma_f32_16x16x32_bf16(kf1, qf[mt][1], a, 0, 0,
                                                    0);
        const float p0 = fexp2(a[0]);  // masked keys: exact 0
        const float p1 = fexp2(a[1]);
        const float p2 = fexp2(a[2]);
        const float p3 = fexp2(a[3]);
        lp[mt] += (p0 + p1) + (p2 + p3);
        const u64 pk = (u64)pkbf(p0, p1) | ((u64)pkbf(p2, p3) << 32);
        pb[mt][nt] = __builtin_bit_cast(s4v, pk);
      }
    }
    // O^T += V^T . P^T  (V A-frags read once per (kh,dt,kc), 2 mt reuse)
#pragma unroll
    for (int kh = 0; kh < 2; ++kh) {
      const u16* vtc = &vt[cur][kh][0];
#pragma unroll
      for (int dt = 0; dt < 4; ++dt) {
        const int vrow = dt * 16 + ln;
        const int vbase = vrow * 64 + (q & 1) * 4;
        const int rx = vrow & 7;
        s4v av[4];
#pragma unroll
        for (int kc = 0; kc < 4; ++kc)
          av[kc] =
              *(const s4v*)(vtc + vbase + (((kc * 2 + (q >> 1)) ^ rx) * 8));
#pragma unroll
        for (int kc = 0; kc < 4; ++kc)
#pragma unroll
          for (int mt = 0; mt < 2; ++mt)
            ot[mt][dt] = mfma16(av[kc], pb[mt][kh * 4 + kc], ot[mt][dt]);
      }
    }
  }
  // row-sum: reduce across the 4 quads (same qrow), normalize, store
#pragma unroll
  for (int mt = 0; mt < 2; ++mt) {
    lp[mt] += __shfl_xor(lp[mt], 16);
    lp[mt] += __shfl_xor(lp[mt], 32);
    const float linv =
        (mb[lq + mt * 16 + ln] > -100.0f) ? (1.0f / lp[mt]) : 0.0f;
#pragma unroll
    for (int dt = 0; dt < 4; ++dt) {
      const u64 pk =
          (u64)pkbf(ot[mt][dt][0] * linv, ot[mt][dt][1] * linv) |
          ((u64)pkbf(ot[mt][dt][2] * linv, ot[mt][dt][3] * linv) << 32);
      *(u64*)(Hd + (size_t)(b * L + lq + mt * 16 + ln) * E + h * DK + dt * 16 +
              q * 4) = pk;
    }
  }
}

// ---------- Kernel 3: output projection as GEMM ----------
__global__ __launch_bounds__(256, 2) void k_projg(const u16* __restrict__ WoT,
                                                  const u16* __restrict__ Hd,
                                                  float* __restrict__ out) {
  __shared__ u16 As[64 * 64];   // 8 KB
  __shared__ u16 Bs[128 * 64];  // 16 KB
  const int bm = blockIdx.x, bn = blockIdx.y;
  f4 acc[2][4];
#pragma unroll
  for (int mt = 0; mt < 2; ++mt)
#pragma unroll
    for (int nt = 0; nt < 4; ++nt) acc[mt][nt] = (f4){0.f, 0.f, 0.f, 0.f};
  gemm_tile<64>(WoT, Hd, bm * 64, bn * 128, As, Bs, acc);

  const int tid = threadIdx.x, wid = tid >> 6, lane = tid & 63;
  const int q = lane >> 4, ln = lane & 15;
  const int wr = wid >> 1, wc = wid & 1;
#pragma unroll
  for (int mt = 0; mt < 2; ++mt)
#pragma unroll
    for (int nt = 0; nt < 4; ++nt)
#pragma unroll
      for (int r = 0; r < 4; ++r) {
        const int d = bm * 64 + wr * 32 + mt * 16 + q * 4 + r;
        const int n = bn * 128 + wc * 64 + nt * 16 + ln;
        const int bb = n >> 11, l = n & 2047;
        out[((size_t)(bb * D + d)) * L + l] = acc[mt][nt][r];
      }
}

extern "C" void kernel_launch(void* const* d_in, const int* in_sizes, int n_in,
                              void* d_out, int out_size, void* d_ws,
                              size_t ws_size, hipStream_t stream) {
  const float* x    = (const float*)d_in[0];
  const float* mask = (const float*)d_in[1];
  const float* Wq   = (const float*)d_in[2];
  const float* Wk   = (const float*)d_in[3];
  const float* Wv   = (const float*)d_in[4];
  const float* Wo   = (const float*)d_in[5];
  u16* ws = (u16*)d_ws;
  u16* Qws  = ws;              // 4194304
  u16* Kws  = ws + 4194304;    // 4194304
  u16* Vtws = ws + 8388608;    // 4194304
  u16* WoTw = ws + 12582912;   // 1048576
  u16* Wtws = ws + 13631488;   // 3145728
  u16* xtws = ws + 16777216;   // 4194304 (xt dead after k_qkvg)
  u16* Hdws = ws + 16777216;   // alias of xt

  k_prep<<<2048, 256, 0, stream>>>(x, Wq, Wk, Wv, Wo, xtws, Wtws, WoTw);
  k_qkvg<<<dim3(32, 24), 256, 0, stream>>>(xtws, Wtws, Qws, Kws, Vtws);
  k_attn<<<dim3(16, 16, 2), 256, 0, stream>>>(Qws, Kws, Vtws, mask, Hdws);
  k_projg<<<dim3(16, 32), 256, 0, stream>>>(WoTw, Hdws, (float*)d_out);
}